// Round 10
// baseline (227.555 us; speedup 1.0000x reference)
//
#include <hip/hip_runtime.h>

// VQ codebook assignment via split-f16 MFMA GEMM — LDS-resident E, barrier-free K-loop,
// per-wave K-rotation, 2-deep phase-head register pipeline (A from global, E from LDS).
//   x:       [B=32, C=256, H=32, W=32] f32   -> tokens [32768][256]
//   embed_w: [K=2048, C=256] f32
// out f32: quantize [32,256,32,32] (8388608) | embed_index [32,32,32] (32768 as float) | loss [1]=0
//
// Math (verified R2-R9): e' = 8192*e; eh=f16(e'), el=f16((e'-eh)*4096); xh=f16(x), xl=f16((x-xh)*4096).
//   8192*dot = acc1 + acc2/4096,  acc1 = sum xh*eh, acc2 = sum(xh*el + xl*eh)
//   d' = 8192*esq - 2*acc1 - 2^-11*acc2 ; argmin_k d' == argmin_k (esq - 2 dot)  (err ~2^-24 rel)
//
// R10 theory: per-wave A delivery (8KB/phase vs ~225cy L2 latency with 8 loads in flight)
// was exactly marginal -> all loads for phase i+1 now issue at the HEAD of phase i into an
// alternate register set (full-phase slack, 2x outstanding). Occupancy is LDS-capped
// (2 waves/SIMD), so +64 VGPR is free. R3: no global_load_lds. R4/R8: no reg caps.
//
// ws fragment-panel layout:
//   A: [panel 512][kc 8][limb 2][slot 4][row 64][16B]  = 32 MB   (64 tokens/panel)
//   E: [panel 32 ][kc 8][limb 2][slot 4][row 64][16B]  =  2 MB   (64 codes/panel)

#define CDIM 256
#define KDIM 2048
#define HW   1024
#define NTOK 32768
#define QOFF 8388608
#define LOFF (QOFF + NTOK)

typedef _Float16 f16x8 __attribute__((ext_vector_type(8)));
typedef float    f32x4 __attribute__((ext_vector_type(4)));

__device__ __forceinline__ f16x8 ld16(const char* p) { return *(const f16x8*)(p); }
__device__ __forceinline__ f16x8 ld16nt(const char* p) {
    return __builtin_nontemporal_load((const f16x8*)(p));
}

// ---------------- fused prep: blocks 0..1023 = X transpose, 1024..1279 = E limbs ----------------
__global__ __launch_bounds__(256) void prep_kernel(const float* __restrict__ x,
                                                   const float* __restrict__ ew,
                                                   char* __restrict__ Aws,
                                                   char* __restrict__ Ews,
                                                   float* __restrict__ esq,
                                                   float* __restrict__ out) {
    __shared__ float tile[32][257];
    const int t = threadIdx.x;
    if (blockIdx.x < 1024) {
        const int bid = blockIdx.x;              // 32 b * 8 kc * 4 hwblk
        const int b = bid >> 5;
        const int kc = (bid >> 2) & 7;
        const int c0 = kc * 32;
        const int hw0 = (bid & 3) * 256;
        #pragma unroll 8
        for (int r = 0; r < 32; ++r)
            tile[r][t] = x[((size_t)(b * CDIM + c0 + r) << 10) + hw0 + t];
        __syncthreads();
        union { _Float16 h[32]; uint4 q[4]; } Hb, Lb;
        #pragma unroll 8
        for (int r = 0; r < 32; ++r) {
            const float xv = tile[r][t];
            const _Float16 hh = (_Float16)xv;
            Hb.h[r] = hh;
            Lb.h[r] = (_Float16)((xv - (float)hh) * 4096.0f);
        }
        const int tok = b * HW + hw0 + t;
        const int p = tok >> 6, row = tok & 63;
        char* d = Aws + (size_t)p * 65536 + kc * 8192 + row * 16;
        #pragma unroll
        for (int g = 0; g < 4; ++g) {
            *(uint4*)(d + g * 1024)        = Hb.q[g];   // high limb
            *(uint4*)(d + 4096 + g * 1024) = Lb.q[g];   // low limb
        }
    } else {
        const int bid = blockIdx.x - 1024;             // 256 blocks x 8 codes
        const int code = bid * 8 + (t >> 5);
        const int u = t & 31;
        const float4 v0 = *(const float4*)&ew[(size_t)code * CDIM + u * 8];
        const float4 v1 = *(const float4*)&ew[(size_t)code * CDIM + u * 8 + 4];
        float s = v0.x*v0.x + v0.y*v0.y + v0.z*v0.z + v0.w*v0.w
                + v1.x*v1.x + v1.y*v1.y + v1.z*v1.z + v1.w*v1.w;
        #pragma unroll
        for (int m = 16; m >= 1; m >>= 1) s += __shfl_xor(s, m, 32);
        if (u == 0) esq[code] = s * 8192.0f;
        const float e[8] = {v0.x, v0.y, v0.z, v0.w, v1.x, v1.y, v1.z, v1.w};
        union { _Float16 h[8]; uint4 q; } H, L;
        #pragma unroll
        for (int j = 0; j < 8; ++j) {
            const float ev = e[j] * 8192.0f;
            const _Float16 hh = (_Float16)ev;
            H.h[j] = hh;
            L.h[j] = (_Float16)((ev - (float)hh) * 4096.0f);
        }
        const int kc = u >> 2, g = u & 3;
        const int p = code >> 6, row = code & 63;
        char* d = Ews + (size_t)p * 65536 + kc * 8192 + g * 1024 + row * 16;
        *(uint4*)d = H.q;
        *(uint4*)(d + 4096) = L.q;
        if (bid == 0 && t == 0) out[LOFF] = 0.0f;
    }
}

// ---------------- fused MFMA GEMM + argmin: 2-deep phase-head pipeline ----------------
// Block = 4 waves x 64 tokens (256 tokens) over ONE shared 64-code panel in LDS.
__global__ __launch_bounds__(256, 2) void vqmm_kernel(const char* __restrict__ Aws,
                                                      const char* __restrict__ Ews,
                                                      const float* __restrict__ esq,
                                                      float* __restrict__ cv,
                                                      int* __restrict__ ci) {
    __shared__ __align__(16) char elds[65536];   // [kc 8][limb 2][slot 4][code 64][16B]

    const int t = threadIdx.x;
    const int bid = blockIdx.x;
    // bijective XCD-grouped swizzle: all 32 code-panels of one token-group share bid%8
    const int by = (bid & 7) | ((bid >> 8) << 3);   // token group 0..127 (256 tokens)
    const int bx = (bid >> 3) & 31;                 // code panel 0..31   (64 codes)
    const int lane = t & 63, w = t >> 6;
    const int g = lane >> 4, lr = lane & 15;
    const int kc0 = (2 * (bid + w)) & 7;            // per-wave phase rotation (anti-lockstep)

    const char* pa = Aws + (size_t)(by * 4 + w) * 65536 + g * 1024 + lr * 16;

    // stage E panel (64 KB) into LDS
    {
        const char* esrc = Ews + (size_t)bx * 65536;
        #pragma unroll
        for (int j = 0; j < 16; ++j) {
            const int off = j * 4096 + t * 16;
            *(uint4*)(elds + off) = *(const uint4*)(esrc + off);
        }
    }

    f16x8 faA[4], fbA[4], faB[4], fbB[4], ecA[4], edA[4], ecB[4], edB[4];
    // A frags for first phase into set A (issued before the barrier; global only)
    {
        const char* pa0 = pa + kc0 * 8192;
        #pragma unroll
        for (int m = 0; m < 4; ++m) {
            faA[m] = ld16nt(pa0 + m * 256);
            fbA[m] = ld16nt(pa0 + 4096 + m * 256);
        }
    }
    __syncthreads();   // the only block-wide barrier

    const f32x4 zf = {0.f, 0.f, 0.f, 0.f};
    f32x4 acc1[4][4], acc2[4][4];
    #pragma unroll
    for (int m = 0; m < 4; ++m)
        #pragma unroll
        for (int n = 0; n < 4; ++n) { acc1[m][n] = zf; acc2[m][n] = zf; }

    const char* el0 = elds + g * 1024 + lr * 16;
    // E frags for first phase into set A (LDS; ~120cy exposed once at loop head)
    {
        const char* ep0 = el0 + kc0 * 8192;
        #pragma unroll
        for (int n = 0; n < 4; ++n) {
            ecA[n] = ld16(ep0 + n * 256);
            edA[n] = ld16(ep0 + 4096 + n * 256);
        }
    }

    // One phase: prefetch (into PF set) ALL loads for phase I+1 at the head, then 48 MFMAs
    // on the CUR set. Full-phase slack for the 8 global A-loads (2x the old margin).
#define VQ_PHASE(CURFA, CURFB, CUREC, CURED, PFFA, PFFB, PFEC, PFED, I)                         \
    {                                                                                            \
        if ((I) < 7) {                                                                           \
            const int kcn = (kc0 + (I) + 1) & 7;                                                 \
            const char* pan = pa + kcn * 8192;                                                   \
            _Pragma("unroll")                                                                    \
            for (int m = 0; m < 4; ++m) {                                                        \
                PFFA[m] = ld16nt(pan + m * 256);                                                 \
                PFFB[m] = ld16nt(pan + 4096 + m * 256);                                          \
            }                                                                                    \
            const char* en = el0 + kcn * 8192;                                                   \
            _Pragma("unroll")                                                                    \
            for (int n = 0; n < 4; ++n) {                                                        \
                PFEC[n] = ld16(en + n * 256);                                                    \
                PFED[n] = ld16(en + 4096 + n * 256);                                             \
            }                                                                                    \
        }                                                                                        \
        _Pragma("unroll")                                                                        \
        for (int m = 0; m < 4; ++m) {                                                            \
            __builtin_amdgcn_s_setprio(1);                                                       \
            _Pragma("unroll")                                                                    \
            for (int n = 0; n < 4; ++n) {                                                        \
                acc1[m][n] = __builtin_amdgcn_mfma_f32_16x16x32_f16(CURFA[m], CUREC[n], acc1[m][n], 0, 0, 0); \
                acc2[m][n] = __builtin_amdgcn_mfma_f32_16x16x32_f16(CURFA[m], CURED[n], acc2[m][n], 0, 0, 0); \
                acc2[m][n] = __builtin_amdgcn_mfma_f32_16x16x32_f16(CURFB[m], CUREC[n], acc2[m][n], 0, 0, 0); \
            }                                                                                    \
            __builtin_amdgcn_s_setprio(0);                                                       \
        }                                                                                        \
    }

    VQ_PHASE(faA, fbA, ecA, edA, faB, fbB, ecB, edB, 0)
    VQ_PHASE(faB, fbB, ecB, edB, faA, fbA, ecA, edA, 1)
    VQ_PHASE(faA, fbA, ecA, edA, faB, fbB, ecB, edB, 2)
    VQ_PHASE(faB, fbB, ecB, edB, faA, fbA, ecA, edA, 3)
    VQ_PHASE(faA, fbA, ecA, edA, faB, fbB, ecB, edB, 4)
    VQ_PHASE(faB, fbB, ecB, edB, faA, fbA, ecA, edA, 5)
    VQ_PHASE(faA, fbA, ecA, edA, faB, fbB, ecB, edB, 6)
    VQ_PHASE(faB, fbB, ecB, edB, faA, fbA, ecA, edA, 7)
#undef VQ_PHASE

    // epilogue: per-wave argmin over its 64 codes; waves own disjoint tokens -> no merge
    float eq[4];
    #pragma unroll
    for (int n = 0; n < 4; ++n) eq[n] = esq[bx * 64 + n * 16 + lr];
    #pragma unroll
    for (int m = 0; m < 4; ++m) {
        #pragma unroll
        for (int r = 0; r < 4; ++r) {
            float bv = 3.4e38f; int bi = 0x7fffffff;
            #pragma unroll
            for (int n = 0; n < 4; ++n) {
                const float d = fmaf(-2.0f, acc1[m][n][r],
                                fmaf(-4.8828125e-4f, acc2[m][n][r], eq[n]));
                const int cidx = bx * 64 + n * 16 + lr;
                if (d < bv) { bv = d; bi = cidx; }
            }
            #pragma unroll
            for (int mk = 1; mk < 16; mk <<= 1) {
                const float ov = __shfl_xor(bv, mk, 16);
                const int   oi = __shfl_xor(bi, mk, 16);
                if (ov < bv || (ov == bv && oi < bi)) { bv = ov; bi = oi; }
            }
            if (lr == 0) {
                const size_t o = (size_t)bx * NTOK + by * 256 + w * 64 + m * 16 + g * 4 + r;
                cv[o] = bv; ci[o] = bi;
            }
        }
    }
}

// ---------------- merge 32 candidates + gather quantize ----------------
__global__ __launch_bounds__(256) void merge_gather_kernel(const float* __restrict__ cv,
                                                           const int* __restrict__ ci,
                                                           const float* __restrict__ ew,
                                                           float* __restrict__ out) {
    __shared__ int sIdx[64];
    const int t = threadIdx.x;
    const int n0 = blockIdx.x * 64;
    if (t < 64) {
        const int tok = n0 + t;
        float bv = cv[tok]; int bi = ci[tok];
        #pragma unroll
        for (int s = 1; s < 32; ++s) {
            const float v = cv[(size_t)s * NTOK + tok];
            const int   i2 = ci[(size_t)s * NTOK + tok];
            if (v < bv || (v == bv && i2 < bi)) { bv = v; bi = i2; }
        }
        sIdx[t] = bi;
        out[QOFF + tok] = (float)bi;
    }
    __syncthreads();
    const int b = n0 >> 10, hw0 = n0 & (HW - 1);
    const int i = t & 63, cg = t >> 6;
    const int kidx = sIdx[i];
    const float* er = ew + (size_t)kidx * CDIM;
    float* ob = out + (size_t)b * CDIM * HW + hw0 + i;
    #pragma unroll
    for (int p = 0; p < CDIM / 4; ++p) {
        const int c = cg * 64 + p;
        ob[(size_t)c * HW] = er[c];
    }
}

extern "C" void kernel_launch(void* const* d_in, const int* in_sizes, int n_in,
                              void* d_out, int out_size, void* d_ws, size_t ws_size,
                              hipStream_t stream) {
    const float* x  = (const float*)d_in[0];
    const float* ew = (const float*)d_in[1];
    float* out = (float*)d_out;
    char* ws = (char*)d_ws;

    char*  Aws = ws;                                // 33,554,432 B
    char*  Ews = ws + 33554432;                     //  2,097,152 B
    float* esq = (float*)(ws + 35651584);           //      8,192 B
    float* cvv = (float*)(ws + 35659776);           //  4,194,304 B (32 sets)
    int*   cii = (int*)(ws + 39854080);             //  4,194,304 B

    prep_kernel<<<1280, 256, 0, stream>>>(x, ew, Aws, Ews, esq, out);
    vqmm_kernel<<<4096, 256, 0, stream>>>(Aws, Ews, esq, cvv, cii);
    merge_gather_kernel<<<NTOK / 64, 256, 0, stream>>>(cvv, cii, ew, out);
}

// Round 11
// 163.986 us; speedup vs baseline: 1.3876x; 1.3876x over previous
//
#include <hip/hip_runtime.h>

// VQ codebook assignment via merged single-accumulator split-f16 MFMA GEMM (K=768 effective).
//   x:       [B=32, C=256, H=32, W=32] f32   -> tokens [32768][256]
//   embed_w: [K=2048, C=256] f32
// out f32: quantize [32,256,32,32] (8388608) | embed_index [32,32,32] (32768 as float) | loss [1]=0
//
// Math (R11): xh=f16(64x), xl=f16(64x-xh); eh=f16(2^15 e), el=f16(2^15 e - eh).
//   acc = sum xh*eh + xh*el + xl*eh  ==  2^21*dot(x,e) - sum(xl*el)   (dropped term ~1e-6 rel)
//   d = 2^21*esq - 2*acc ; argmin_k d == argmin_k (esq - 2 dot).
//   Scales keep limbs out of f16-denormal range (subnorm fraction <1%, error << argmin gap).
//   ONE f32 accumulator (64 regs) instead of two (128) -> 2-deep pipeline fits 256-reg budget.
//
// Register budget law (R4/R8/R10 spills): per-SIMD unified pool 512; 2 waves/SIMD -> 256/wave.
//   acc 64 (AGPR) + A-frags 2 sets 64 + E-frags 2 sets 64 + addr ~15 = ~210. OK.
// R3: no global_load_lds (kills L2 reuse). R9: per-wave K-rotation + setprio (proven +16%).
//
// ws fragment-panel layout:
//   A: [panel 512][kc 8][limb 2][slot 4][row 64][16B]  = 32 MB   (64 tokens/panel)
//   E: [panel 32 ][kc 8][limb 2][slot 4][row 64][16B]  =  2 MB   (64 codes/panel)

#define CDIM 256
#define KDIM 2048
#define HW   1024
#define NTOK 32768
#define QOFF 8388608
#define LOFF (QOFF + NTOK)

typedef _Float16 f16x8 __attribute__((ext_vector_type(8)));
typedef float    f32x4 __attribute__((ext_vector_type(4)));

__device__ __forceinline__ f16x8 ld16(const char* p) { return *(const f16x8*)(p); }
__device__ __forceinline__ f16x8 ld16nt(const char* p) {
    return __builtin_nontemporal_load((const f16x8*)(p));
}

// ---------------- fused prep: blocks 0..1023 = X transpose, 1024..1279 = E limbs ----------------
__global__ __launch_bounds__(256) void prep_kernel(const float* __restrict__ x,
                                                   const float* __restrict__ ew,
                                                   char* __restrict__ Aws,
                                                   char* __restrict__ Ews,
                                                   float* __restrict__ esq,
                                                   float* __restrict__ out) {
    __shared__ float tile[32][257];
    const int t = threadIdx.x;
    if (blockIdx.x < 1024) {
        const int bid = blockIdx.x;              // 32 b * 8 kc * 4 hwblk
        const int b = bid >> 5;
        const int kc = (bid >> 2) & 7;
        const int c0 = kc * 32;
        const int hw0 = (bid & 3) * 256;
        #pragma unroll 8
        for (int r = 0; r < 32; ++r)
            tile[r][t] = x[((size_t)(b * CDIM + c0 + r) << 10) + hw0 + t];
        __syncthreads();
        union { _Float16 h[32]; uint4 q[4]; } Hb, Lb;
        #pragma unroll 8
        for (int r = 0; r < 32; ++r) {
            const float xs = tile[r][t] * 64.0f;
            const _Float16 hh = (_Float16)xs;
            Hb.h[r] = hh;
            Lb.h[r] = (_Float16)(xs - (float)hh);
        }
        const int tok = b * HW + hw0 + t;
        const int p = tok >> 6, row = tok & 63;
        char* d = Aws + (size_t)p * 65536 + kc * 8192 + row * 16;
        #pragma unroll
        for (int g = 0; g < 4; ++g) {
            *(uint4*)(d + g * 1024)        = Hb.q[g];   // high limb
            *(uint4*)(d + 4096 + g * 1024) = Lb.q[g];   // low limb
        }
    } else {
        const int bid = blockIdx.x - 1024;             // 256 blocks x 8 codes
        const int code = bid * 8 + (t >> 5);
        const int u = t & 31;
        const float4 v0 = *(const float4*)&ew[(size_t)code * CDIM + u * 8];
        const float4 v1 = *(const float4*)&ew[(size_t)code * CDIM + u * 8 + 4];
        float s = v0.x*v0.x + v0.y*v0.y + v0.z*v0.z + v0.w*v0.w
                + v1.x*v1.x + v1.y*v1.y + v1.z*v1.z + v1.w*v1.w;
        #pragma unroll
        for (int m = 16; m >= 1; m >>= 1) s += __shfl_xor(s, m, 32);
        if (u == 0) esq[code] = s * 2097152.0f;        // 2^21 * esq
        const float e[8] = {v0.x, v0.y, v0.z, v0.w, v1.x, v1.y, v1.z, v1.w};
        union { _Float16 h[8]; uint4 q; } H, L;
        #pragma unroll
        for (int j = 0; j < 8; ++j) {
            const float ev = e[j] * 32768.0f;          // 2^15 * e
            const _Float16 hh = (_Float16)ev;
            H.h[j] = hh;
            L.h[j] = (_Float16)(ev - (float)hh);
        }
        const int kc = u >> 2, g = u & 3;
        const int p = code >> 6, row = code & 63;
        char* d = Ews + (size_t)p * 65536 + kc * 8192 + g * 1024 + row * 16;
        *(uint4*)d = H.q;
        *(uint4*)(d + 4096) = L.q;
        if (bid == 0 && t == 0) out[LOFF] = 0.0f;
    }
}

// ---------------- fused MFMA GEMM + argmin: merged acc, full 2-deep phase-head pipeline ----------------
// Block = 4 waves x 64 tokens (256 tokens) over ONE shared 64-code panel in LDS.
__global__ __launch_bounds__(256, 2) void vqmm_kernel(const char* __restrict__ Aws,
                                                      const char* __restrict__ Ews,
                                                      const float* __restrict__ esq,
                                                      float* __restrict__ cv,
                                                      int* __restrict__ ci) {
    __shared__ __align__(16) char elds[65536];   // [kc 8][limb 2][slot 4][code 64][16B]

    const int t = threadIdx.x;
    const int bid = blockIdx.x;
    // bijective XCD-grouped swizzle: all 32 code-panels of one token-group share bid%8
    const int by = (bid & 7) | ((bid >> 8) << 3);   // token group 0..127 (256 tokens)
    const int bx = (bid >> 3) & 31;                 // code panel 0..31   (64 codes)
    const int lane = t & 63, w = t >> 6;
    const int g = lane >> 4, lr = lane & 15;
    const int kc0 = (2 * (bid + w)) & 7;            // per-wave phase rotation (anti-lockstep)

    const char* pa = Aws + (size_t)(by * 4 + w) * 65536 + g * 1024 + lr * 16;

    // stage E panel (64 KB) into LDS
    {
        const char* esrc = Ews + (size_t)bx * 65536;
        #pragma unroll
        for (int j = 0; j < 16; ++j) {
            const int off = j * 4096 + t * 16;
            *(uint4*)(elds + off) = *(const uint4*)(esrc + off);
        }
    }

    f16x8 faA[4], fbA[4], faB[4], fbB[4], ec[2][4], ed[2][4];
    // A frags for first phase into set A (issued before the barrier; global only)
    {
        const char* pa0 = pa + kc0 * 8192;
        #pragma unroll
        for (int m = 0; m < 4; ++m) {
            faA[m] = ld16nt(pa0 + m * 256);
            fbA[m] = ld16nt(pa0 + 4096 + m * 256);
        }
    }
    __syncthreads();   // the only block-wide barrier

    const f32x4 zf = {0.f, 0.f, 0.f, 0.f};
    f32x4 acc[4][4];
    #pragma unroll
    for (int m = 0; m < 4; ++m)
        #pragma unroll
        for (int n = 0; n < 4; ++n) acc[m][n] = zf;

    const char* el0 = elds + g * 1024 + lr * 16;
    // E frags for first phase (LDS; ~120cy exposed once at loop head)
    {
        const char* ep0 = el0 + kc0 * 8192;
        #pragma unroll
        for (int n = 0; n < 4; ++n) {
            ec[0][n] = ld16(ep0 + n * 256);
            ed[0][n] = ld16(ep0 + 4096 + n * 256);
        }
    }

    // One phase: at the head, issue ALL loads for phase I+1 (A -> PF reg set, E -> nxt set),
    // then 48 MFMAs on the CUR sets. Full-phase slack for the 8 global A-loads.
#define VQ_PHASE(CFA, CFB, PFA, PFB, CUR, NXT, I)                                               \
    {                                                                                            \
        if ((I) < 7) {                                                                           \
            const int kcn = (kc0 + (I) + 1) & 7;                                                 \
            const char* pan = pa + kcn * 8192;                                                   \
            _Pragma("unroll")                                                                    \
            for (int m = 0; m < 4; ++m) {                                                        \
                PFA[m] = ld16nt(pan + m * 256);                                                  \
                PFB[m] = ld16nt(pan + 4096 + m * 256);                                           \
            }                                                                                    \
            const char* en = el0 + kcn * 8192;                                                   \
            _Pragma("unroll")                                                                    \
            for (int n = 0; n < 4; ++n) {                                                        \
                ec[NXT][n] = ld16(en + n * 256);                                                 \
                ed[NXT][n] = ld16(en + 4096 + n * 256);                                          \
            }                                                                                    \
        }                                                                                        \
        _Pragma("unroll")                                                                        \
        for (int m = 0; m < 4; ++m) {                                                            \
            __builtin_amdgcn_s_setprio(1);                                                       \
            _Pragma("unroll")                                                                    \
            for (int n = 0; n < 4; ++n) {                                                        \
                acc[m][n] = __builtin_amdgcn_mfma_f32_16x16x32_f16(CFA[m], ec[CUR][n], acc[m][n], 0, 0, 0); \
                acc[m][n] = __builtin_amdgcn_mfma_f32_16x16x32_f16(CFA[m], ed[CUR][n], acc[m][n], 0, 0, 0); \
                acc[m][n] = __builtin_amdgcn_mfma_f32_16x16x32_f16(CFB[m], ec[CUR][n], acc[m][n], 0, 0, 0); \
            }                                                                                    \
            __builtin_amdgcn_s_setprio(0);                                                       \
        }                                                                                        \
    }

    VQ_PHASE(faA, fbA, faB, fbB, 0, 1, 0)
    VQ_PHASE(faB, fbB, faA, fbA, 1, 0, 1)
    VQ_PHASE(faA, fbA, faB, fbB, 0, 1, 2)
    VQ_PHASE(faB, fbB, faA, fbA, 1, 0, 3)
    VQ_PHASE(faA, fbA, faB, fbB, 0, 1, 4)
    VQ_PHASE(faB, fbB, faA, fbA, 1, 0, 5)
    VQ_PHASE(faA, fbA, faB, fbB, 0, 1, 6)
    VQ_PHASE(faB, fbB, faA, fbA, 1, 0, 7)
#undef VQ_PHASE

    // epilogue: per-wave argmin over its 64 codes; waves own disjoint tokens -> no merge
    float eq[4];
    #pragma unroll
    for (int n = 0; n < 4; ++n) eq[n] = esq[bx * 64 + n * 16 + lr];
    #pragma unroll
    for (int m = 0; m < 4; ++m) {
        #pragma unroll
        for (int r = 0; r < 4; ++r) {
            float bv = 3.4e38f; int bi = 0x7fffffff;
            #pragma unroll
            for (int n = 0; n < 4; ++n) {
                const float d = fmaf(-2.0f, acc[m][n][r], eq[n]);
                const int cidx = bx * 64 + n * 16 + lr;
                if (d < bv) { bv = d; bi = cidx; }
            }
            #pragma unroll
            for (int mk = 1; mk < 16; mk <<= 1) {
                const float ov = __shfl_xor(bv, mk, 16);
                const int   oi = __shfl_xor(bi, mk, 16);
                if (ov < bv || (ov == bv && oi < bi)) { bv = ov; bi = oi; }
            }
            if (lr == 0) {
                const size_t o = (size_t)bx * NTOK + by * 256 + w * 64 + m * 16 + g * 4 + r;
                cv[o] = bv; ci[o] = bi;
            }
        }
    }
}

// ---------------- merge 32 candidates + gather quantize ----------------
__global__ __launch_bounds__(256) void merge_gather_kernel(const float* __restrict__ cv,
                                                           const int* __restrict__ ci,
                                                           const float* __restrict__ ew,
                                                           float* __restrict__ out) {
    __shared__ int sIdx[64];
    const int t = threadIdx.x;
    const int n0 = blockIdx.x * 64;
    if (t < 64) {
        const int tok = n0 + t;
        float bv = cv[tok]; int bi = ci[tok];
        #pragma unroll
        for (int s = 1; s < 32; ++s) {
            const float v = cv[(size_t)s * NTOK + tok];
            const int   i2 = ci[(size_t)s * NTOK + tok];
            if (v < bv || (v == bv && i2 < bi)) { bv = v; bi = i2; }
        }
        sIdx[t] = bi;
        out[QOFF + tok] = (float)bi;
    }
    __syncthreads();
    const int b = n0 >> 10, hw0 = n0 & (HW - 1);
    const int i = t & 63, cg = t >> 6;
    const int kidx = sIdx[i];
    const float* er = ew + (size_t)kidx * CDIM;
    float* ob = out + (size_t)b * CDIM * HW + hw0 + i;
    #pragma unroll
    for (int p = 0; p < CDIM / 4; ++p) {
        const int c = cg * 64 + p;
        ob[(size_t)c * HW] = er[c];
    }
}

extern "C" void kernel_launch(void* const* d_in, const int* in_sizes, int n_in,
                              void* d_out, int out_size, void* d_ws, size_t ws_size,
                              hipStream_t stream) {
    const float* x  = (const float*)d_in[0];
    const float* ew = (const float*)d_in[1];
    float* out = (float*)d_out;
    char* ws = (char*)d_ws;

    char*  Aws = ws;                                // 33,554,432 B
    char*  Ews = ws + 33554432;                     //  2,097,152 B
    float* esq = (float*)(ws + 35651584);           //      8,192 B
    float* cvv = (float*)(ws + 35659776);           //  4,194,304 B (32 sets)
    int*   cii = (int*)(ws + 39854080);             //  4,194,304 B

    prep_kernel<<<1280, 256, 0, stream>>>(x, ew, Aws, Ews, esq, out);
    vqmm_kernel<<<4096, 256, 0, stream>>>(Aws, Ews, esq, cvv, cii);
    merge_gather_kernel<<<NTOK / 64, 256, 0, stream>>>(cvv, cii, ew, out);
}

// Round 12
// 145.934 us; speedup vs baseline: 1.5593x; 1.1237x over previous
//
#include <hip/hip_runtime.h>

// VQ codebook assignment via merged single-accumulator split-f16 MFMA GEMM (K=768 effective),
// half-K LDS staging -> 32KB LDS -> 3 blocks/CU (12 waves), 1-deep reload-in-place frags.
//   x:       [B=32, C=256, H=32, W=32] f32   -> tokens [32768][256]
//   embed_w: [K=2048, C=256] f32
// out f32: quantize [32,256,32,32] (8388608) | embed_index [32,32,32] (32768 as float) | loss [1]=0
//
// Math (verified R11): xh=f16(64x), xl=f16(64x-xh); eh=f16(2^15 e), el=f16(2^15 e - eh).
//   acc = sum xh*eh + xh*el + xl*eh == 2^21*dot - sum(xl*el)  (dropped ~1e-6 rel)
//   d = 2^21*esq - 2*acc ; argmin preserved.
//
// Register law (R4/R8/R10): per-SIMD unified pool 512 -> 3 waves/SIMD => <=170 regs/wave.
//   acc 64 + A-frags 32 (reload-in-place) + E-frags 32 (reload-in-place) + addr ~20 = ~150. OK.
// R11 falsified in-flight depth (2-deep == 1-deep) -> limiter is TLP at 2 waves/SIMD.
// R3: no global_load_lds. R9: rotation + setprio kept. nt dropped (co-resident blocks
// share A panels via L1: same by, same wave-slot -> same panel).
//
// ws fragment-panel layout:
//   A: [panel 512][kc 8][limb 2][slot 4][row 64][16B]  = 32 MB   (64 tokens/panel)
//   E: [panel 32 ][kc 8][limb 2][slot 4][row 64][16B]  =  2 MB   (64 codes/panel)

#define CDIM 256
#define KDIM 2048
#define HW   1024
#define NTOK 32768
#define QOFF 8388608
#define LOFF (QOFF + NTOK)

typedef _Float16 f16x8 __attribute__((ext_vector_type(8)));
typedef float    f32x4 __attribute__((ext_vector_type(4)));

__device__ __forceinline__ f16x8 ld16(const char* p) { return *(const f16x8*)(p); }

// ---------------- fused prep: blocks 0..1023 = X transpose, 1024..1279 = E limbs ----------------
__global__ __launch_bounds__(256) void prep_kernel(const float* __restrict__ x,
                                                   const float* __restrict__ ew,
                                                   char* __restrict__ Aws,
                                                   char* __restrict__ Ews,
                                                   float* __restrict__ esq,
                                                   float* __restrict__ out) {
    __shared__ float tile[32][257];
    const int t = threadIdx.x;
    if (blockIdx.x < 1024) {
        const int bid = blockIdx.x;              // 32 b * 8 kc * 4 hwblk
        const int b = bid >> 5;
        const int kc = (bid >> 2) & 7;
        const int c0 = kc * 32;
        const int hw0 = (bid & 3) * 256;
        #pragma unroll 8
        for (int r = 0; r < 32; ++r)
            tile[r][t] = x[((size_t)(b * CDIM + c0 + r) << 10) + hw0 + t];
        __syncthreads();
        union { _Float16 h[32]; uint4 q[4]; } Hb, Lb;
        #pragma unroll 8
        for (int r = 0; r < 32; ++r) {
            const float xs = tile[r][t] * 64.0f;
            const _Float16 hh = (_Float16)xs;
            Hb.h[r] = hh;
            Lb.h[r] = (_Float16)(xs - (float)hh);
        }
        const int tok = b * HW + hw0 + t;
        const int p = tok >> 6, row = tok & 63;
        char* d = Aws + (size_t)p * 65536 + kc * 8192 + row * 16;
        #pragma unroll
        for (int g = 0; g < 4; ++g) {
            *(uint4*)(d + g * 1024)        = Hb.q[g];   // high limb
            *(uint4*)(d + 4096 + g * 1024) = Lb.q[g];   // low limb
        }
    } else {
        const int bid = blockIdx.x - 1024;             // 256 blocks x 8 codes
        const int code = bid * 8 + (t >> 5);
        const int u = t & 31;
        const float4 v0 = *(const float4*)&ew[(size_t)code * CDIM + u * 8];
        const float4 v1 = *(const float4*)&ew[(size_t)code * CDIM + u * 8 + 4];
        float s = v0.x*v0.x + v0.y*v0.y + v0.z*v0.z + v0.w*v0.w
                + v1.x*v1.x + v1.y*v1.y + v1.z*v1.z + v1.w*v1.w;
        #pragma unroll
        for (int m = 16; m >= 1; m >>= 1) s += __shfl_xor(s, m, 32);
        if (u == 0) esq[code] = s * 2097152.0f;        // 2^21 * esq
        const float e[8] = {v0.x, v0.y, v0.z, v0.w, v1.x, v1.y, v1.z, v1.w};
        union { _Float16 h[8]; uint4 q; } H, L;
        #pragma unroll
        for (int j = 0; j < 8; ++j) {
            const float ev = e[j] * 32768.0f;          // 2^15 * e
            const _Float16 hh = (_Float16)ev;
            H.h[j] = hh;
            L.h[j] = (_Float16)(ev - (float)hh);
        }
        const int kc = u >> 2, g = u & 3;
        const int p = code >> 6, row = code & 63;
        char* d = Ews + (size_t)p * 65536 + kc * 8192 + g * 1024 + row * 16;
        *(uint4*)d = H.q;
        *(uint4*)(d + 4096) = L.q;
        if (bid == 0 && t == 0) out[LOFF] = 0.0f;
    }
}

// ---------------- fused MFMA GEMM + argmin: 32KB half-K LDS-E, 3 blocks/CU ----------------
// Block = 4 waves x 64 tokens (256 tokens) over ONE shared 64-code panel.
__global__ __launch_bounds__(256, 3) void vqmm_kernel(const char* __restrict__ Aws,
                                                      const char* __restrict__ Ews,
                                                      const float* __restrict__ esq,
                                                      float* __restrict__ cv,
                                                      int* __restrict__ ci) {
    __shared__ __align__(16) char elds[32768];   // one K-half: [kc 4][limb 2][slot 4][code 64][16B]

    const int t = threadIdx.x;
    const int bid = blockIdx.x;
    // bijective XCD-grouped swizzle: all 32 code-panels of one token-group share bid%8
    const int by = (bid & 7) | ((bid >> 8) << 3);   // token group 0..127 (256 tokens)
    const int bx = (bid >> 3) & 31;                 // code panel 0..31   (64 codes)
    const int lane = t & 63, w = t >> 6;
    const int g = lane >> 4, lr = lane & 15;
    const int kc0 = (bid + w) & 3;                  // per-wave rotation within a half

    const char* pa = Aws + (size_t)(by * 4 + w) * 65536 + g * 1024 + lr * 16;
    const char* esrc = Ews + (size_t)bx * 65536;

    f16x8 fa[4], fb[4], ec[4], ed[4];
    // A frags for (h=0, kcl=kc0) — global chunk kc0
    {
        const char* pa0 = pa + kc0 * 8192;
        #pragma unroll
        for (int m = 0; m < 4; ++m) {
            fa[m] = ld16(pa0 + m * 256);
            fb[m] = ld16(pa0 + 4096 + m * 256);
        }
    }
    // stage E half-0 (32 KB): 256 threads x 8 x 16B
    #pragma unroll
    for (int j = 0; j < 8; ++j) {
        const int off = j * 4096 + t * 16;
        *(uint4*)(elds + off) = *(const uint4*)(esrc + off);
    }
    __syncthreads();

    const f32x4 zf = {0.f, 0.f, 0.f, 0.f};
    f32x4 acc[4][4];
    #pragma unroll
    for (int m = 0; m < 4; ++m)
        #pragma unroll
        for (int n = 0; n < 4; ++n) acc[m][n] = zf;

    const char* el0 = elds + g * 1024 + lr * 16;
    // E frags for first phase
    {
        const char* ep0 = el0 + kc0 * 8192;
        #pragma unroll
        for (int n = 0; n < 4; ++n) {
            ec[n] = ld16(ep0 + n * 256);
            ed[n] = ld16(ep0 + 4096 + n * 256);
        }
    }

    #pragma unroll
    for (int h = 0; h < 2; ++h) {
        if (h == 1) {
            __syncthreads();   // all waves done reading half-0
            #pragma unroll
            for (int j = 0; j < 8; ++j) {
                const int off = j * 4096 + t * 16;
                *(uint4*)(elds + off) = *(const uint4*)(esrc + 32768 + off);
            }
            __syncthreads();   // half-1 visible
            const char* ep = el0 + kc0 * 8192;   // E frags for half-1 first phase
            #pragma unroll
            for (int n = 0; n < 4; ++n) {
                ec[n] = ld16(ep + n * 256);
                ed[n] = ld16(ep + 4096 + n * 256);
            }
        }
        #pragma unroll
        for (int i = 0; i < 4; ++i) {
            const bool lastA = (h == 1) && (i == 3);
            // next global A chunk: within half, or first chunk of half-1 (A is global, no barrier dep)
            const int gkcn = (i < 3) ? (h * 4 + ((kc0 + i + 1) & 3)) : (4 + kc0);
            const char* pan = pa + gkcn * 8192;
            #pragma unroll
            for (int m = 0; m < 4; ++m) {
                __builtin_amdgcn_s_setprio(1);
                #pragma unroll
                for (int n = 0; n < 4; ++n) {
                    acc[m][n] = __builtin_amdgcn_mfma_f32_16x16x32_f16(fa[m], ec[n], acc[m][n], 0, 0, 0);
                    acc[m][n] = __builtin_amdgcn_mfma_f32_16x16x32_f16(fa[m], ed[n], acc[m][n], 0, 0, 0);
                    acc[m][n] = __builtin_amdgcn_mfma_f32_16x16x32_f16(fb[m], ec[n], acc[m][n], 0, 0, 0);
                }
                __builtin_amdgcn_s_setprio(0);
                // A reload-in-place for next phase, right after fa[m]/fb[m]'s last use
                if (!lastA) {
                    fa[m] = ld16(pan + m * 256);
                    fb[m] = ld16(pan + 4096 + m * 256);
                }
            }
            // E reload-in-place for next phase within this half (LDS, ~150cy, covered by TLP)
            if (i < 3) {
                const char* en = el0 + ((kc0 + i + 1) & 3) * 8192;
                #pragma unroll
                for (int n = 0; n < 4; ++n) {
                    ec[n] = ld16(en + n * 256);
                    ed[n] = ld16(en + 4096 + n * 256);
                }
            }
        }
    }

    // epilogue: per-wave argmin over its 64 codes; waves own disjoint tokens -> no merge
    float eq[4];
    #pragma unroll
    for (int n = 0; n < 4; ++n) eq[n] = esq[bx * 64 + n * 16 + lr];
    #pragma unroll
    for (int m = 0; m < 4; ++m) {
        #pragma unroll
        for (int r = 0; r < 4; ++r) {
            float bv = 3.4e38f; int bi = 0x7fffffff;
            #pragma unroll
            for (int n = 0; n < 4; ++n) {
                const float d = fmaf(-2.0f, acc[m][n][r], eq[n]);
                const int cidx = bx * 64 + n * 16 + lr;
                if (d < bv) { bv = d; bi = cidx; }
            }
            #pragma unroll
            for (int mk = 1; mk < 16; mk <<= 1) {
                const float ov = __shfl_xor(bv, mk, 16);
                const int   oi = __shfl_xor(bi, mk, 16);
                if (ov < bv || (ov == bv && oi < bi)) { bv = ov; bi = oi; }
            }
            if (lr == 0) {
                const size_t o = (size_t)bx * NTOK + by * 256 + w * 64 + m * 16 + g * 4 + r;
                cv[o] = bv; ci[o] = bi;
            }
        }
    }
}

// ---------------- merge 32 candidates + gather quantize ----------------
__global__ __launch_bounds__(256) void merge_gather_kernel(const float* __restrict__ cv,
                                                           const int* __restrict__ ci,
                                                           const float* __restrict__ ew,
                                                           float* __restrict__ out) {
    __shared__ int sIdx[64];
    const int t = threadIdx.x;
    const int n0 = blockIdx.x * 64;
    if (t < 64) {
        const int tok = n0 + t;
        float bv = cv[tok]; int bi = ci[tok];
        #pragma unroll
        for (int s = 1; s < 32; ++s) {
            const float v = cv[(size_t)s * NTOK + tok];
            const int   i2 = ci[(size_t)s * NTOK + tok];
            if (v < bv || (v == bv && i2 < bi)) { bv = v; bi = i2; }
        }
        sIdx[t] = bi;
        out[QOFF + tok] = (float)bi;
    }
    __syncthreads();
    const int b = n0 >> 10, hw0 = n0 & (HW - 1);
    const int i = t & 63, cg = t >> 6;
    const int kidx = sIdx[i];
    const float* er = ew + (size_t)kidx * CDIM;
    float* ob = out + (size_t)b * CDIM * HW + hw0 + i;
    #pragma unroll
    for (int p = 0; p < CDIM / 4; ++p) {
        const int c = cg * 64 + p;
        ob[(size_t)c * HW] = er[c];
    }
}

extern "C" void kernel_launch(void* const* d_in, const int* in_sizes, int n_in,
                              void* d_out, int out_size, void* d_ws, size_t ws_size,
                              hipStream_t stream) {
    const float* x  = (const float*)d_in[0];
    const float* ew = (const float*)d_in[1];
    float* out = (float*)d_out;
    char* ws = (char*)d_ws;

    char*  Aws = ws;                                // 33,554,432 B
    char*  Ews = ws + 33554432;                     //  2,097,152 B
    float* esq = (float*)(ws + 35651584);           //      8,192 B
    float* cvv = (float*)(ws + 35659776);           //  4,194,304 B (32 sets)
    int*   cii = (int*)(ws + 39854080);             //  4,194,304 B

    prep_kernel<<<1280, 256, 0, stream>>>(x, ew, Aws, Ews, esq, out);
    vqmm_kernel<<<4096, 256, 0, stream>>>(Aws, Ews, esq, cvv, cii);
    merge_gather_kernel<<<NTOK / 64, 256, 0, stream>>>(cvv, cii, ew, out);
}